// Round 1
// baseline (6301.883 us; speedup 1.0000x reference)
//
#include <hip/hip_runtime.h>
#include <hip/hip_bf16.h>

#define N_NODES  100000
#define N_HEDGES 50000
#define NNZ      1600000
#define IN_C     128
#define HID_C    128
#define N_CLS    8

// ---------------- degree counts ----------------
__global__ void k_degrees(const int* __restrict__ nidx, const int* __restrict__ eidx,
                          float* __restrict__ D, float* __restrict__ B) {
    int i = blockIdx.x * blockDim.x + threadIdx.x;
    if (i < NNZ) {
        atomicAdd(&D[nidx[i]], 1.0f);
        atomicAdd(&B[eidx[i]], 1.0f);
    }
}

// ---------------- GEMM1: XW = X @ W1  (100000x128 @ 128x128), fp32 ----------------
// block = 256 threads (16x16), tile 64 rows x 128 cols, thread tile 4x8, K-step 32
__global__ __launch_bounds__(256) void k_gemm1(const float* __restrict__ X,
                                               const float* __restrict__ W,
                                               float* __restrict__ XW) {
    __shared__ float sA[64 * 32];
    __shared__ float sB[32 * 128];
    const int tid = threadIdx.x;
    const int row0 = blockIdx.x * 64;
    const int tx = tid & 15, ty = tid >> 4;

    float acc[4][8];
#pragma unroll
    for (int r = 0; r < 4; r++)
#pragma unroll
        for (int c = 0; c < 8; c++) acc[r][c] = 0.f;

    for (int kt = 0; kt < 128; kt += 32) {
        // load A tile 64x32 (8 floats / thread)
        {
            int idx = tid * 8;
            int ar = idx >> 5, ak = idx & 31;
            int grow = row0 + ar; if (grow >= N_NODES) grow = N_NODES - 1;
            const float4* src = (const float4*)&X[grow * 128 + kt + ak];
            float4 v0 = src[0], v1 = src[1];
            *(float4*)&sA[ar * 32 + ak] = v0;
            *(float4*)&sA[ar * 32 + ak + 4] = v1;
        }
        // load B tile 32x128 (16 floats / thread)
        {
            int idx = tid * 16;
            int br = idx >> 7, bc = idx & 127;
            const float4* src = (const float4*)&W[(kt + br) * 128 + bc];
            float4 v0 = src[0], v1 = src[1], v2 = src[2], v3 = src[3];
            *(float4*)&sB[br * 128 + bc]      = v0;
            *(float4*)&sB[br * 128 + bc + 4]  = v1;
            *(float4*)&sB[br * 128 + bc + 8]  = v2;
            *(float4*)&sB[br * 128 + bc + 12] = v3;
        }
        __syncthreads();
#pragma unroll
        for (int kk = 0; kk < 32; kk++) {
            float a[4], b[8];
#pragma unroll
            for (int r = 0; r < 4; r++) a[r] = sA[(ty * 4 + r) * 32 + kk];
#pragma unroll
            for (int j = 0; j < 8; j++) b[j] = sB[kk * 128 + tx * 8 + j];
#pragma unroll
            for (int r = 0; r < 4; r++)
#pragma unroll
                for (int j = 0; j < 8; j++) acc[r][j] = fmaf(a[r], b[j], acc[r][j]);
        }
        __syncthreads();
    }
#pragma unroll
    for (int r = 0; r < 4; r++) {
        int grow = row0 + ty * 4 + r;
        if (grow < N_NODES) {
            float4 v0 = make_float4(acc[r][0], acc[r][1], acc[r][2], acc[r][3]);
            float4 v1 = make_float4(acc[r][4], acc[r][5], acc[r][6], acc[r][7]);
            *(float4*)&XW[grow * 128 + tx * 8]     = v0;
            *(float4*)&XW[grow * 128 + tx * 8 + 4] = v1;
        }
    }
}

// ---------------- scatter node->edge, 128 ch: S[e] += xw[v]  (32 thr / nz) ----------------
__global__ void k_scatter_ve(const int* __restrict__ nidx, const int* __restrict__ eidx,
                             const float* __restrict__ xw, float* __restrict__ S) {
    int t = blockIdx.x * blockDim.x + threadIdx.x;
    int nz = t >> 5;
    int c4 = (t & 31) << 2;
    if (nz < NNZ) {
        int v = nidx[nz], e = eidx[nz];
        float4 val = *(const float4*)&xw[v * 128 + c4];
        float* dst = &S[e * 128 + c4];
        atomicAdd(dst + 0, val.x);
        atomicAdd(dst + 1, val.y);
        atomicAdd(dst + 2, val.z);
        atomicAdd(dst + 3, val.w);
    }
}

// ---------------- scatter edge->node, 128 ch: nacc[v] += Binv[e]*S[e] ----------------
__global__ void k_scatter_ev(const int* __restrict__ nidx, const int* __restrict__ eidx,
                             const float* __restrict__ S, const float* __restrict__ B,
                             float* __restrict__ nacc) {
    int t = blockIdx.x * blockDim.x + threadIdx.x;
    int nz = t >> 5;
    int c4 = (t & 31) << 2;
    if (nz < NNZ) {
        int v = nidx[nz], e = eidx[nz];
        float b = B[e];
        float binv = (b > 0.f) ? 1.f / b : 0.f;
        float4 val = *(const float4*)&S[e * 128 + c4];
        float* dst = &nacc[v * 128 + c4];
        atomicAdd(dst + 0, val.x * binv);
        atomicAdd(dst + 1, val.y * binv);
        atomicAdd(dst + 2, val.z * binv);
        atomicAdd(dst + 3, val.w * binv);
    }
}

// ---------------- finalize layer1: h = relu(nacc*Dinv + b1) ----------------
__global__ void k_finalize1(const float* __restrict__ nacc, const float* __restrict__ D,
                            const float* __restrict__ b1, float* __restrict__ h) {
    int t = blockIdx.x * blockDim.x + threadIdx.x;
    int v = t >> 5;
    int c4 = (t & 31) << 2;
    if (v < N_NODES) {
        float d = D[v];
        float dinv = (d > 0.f) ? 1.f / d : 0.f;
        float4 a = *(const float4*)&nacc[v * 128 + c4];
        float4 bb = *(const float4*)&b1[c4];
        float4 r;
        r.x = fmaxf(fmaf(a.x, dinv, bb.x), 0.f);
        r.y = fmaxf(fmaf(a.y, dinv, bb.y), 0.f);
        r.z = fmaxf(fmaf(a.z, dinv, bb.z), 0.f);
        r.w = fmaxf(fmaf(a.w, dinv, bb.w), 0.f);
        *(float4*)&h[v * 128 + c4] = r;
    }
}

// ---------------- GEMM2: Y = H @ W2  (100000x128 @ 128x8) ----------------
__global__ __launch_bounds__(256) void k_gemm2(const float* __restrict__ H,
                                               const float* __restrict__ W2,
                                               float* __restrict__ Y) {
    __shared__ float sH[32 * 128];
    __shared__ float sW[128 * 8];
    const int tid = threadIdx.x;
    const int row0 = blockIdx.x * 32;
    {
        int i = tid * 4;  // 256*4 = 1024 floats
        *(float4*)&sW[i] = *(const float4*)&W2[i];
    }
    {
        int i = tid * 16;
        int r = i >> 7, c = i & 127;
        int g = row0 + r; if (g >= N_NODES) g = N_NODES - 1;
        const float4* src = (const float4*)&H[g * 128 + c];
        *(float4*)&sH[r * 128 + c]      = src[0];
        *(float4*)&sH[r * 128 + c + 4]  = src[1];
        *(float4*)&sH[r * 128 + c + 8]  = src[2];
        *(float4*)&sH[r * 128 + c + 12] = src[3];
    }
    __syncthreads();
    int r = tid >> 3, col = tid & 7;
    float acc = 0.f;
#pragma unroll
    for (int k = 0; k < 128; k++) acc = fmaf(sH[r * 128 + k], sW[k * 8 + col], acc);
    int g = row0 + r;
    if (g < N_NODES) Y[g * 8 + col] = acc;
}

// ---------------- scatter node->edge, 8 ch (2 thr / nz) ----------------
__global__ void k_scatter_ve2(const int* __restrict__ nidx, const int* __restrict__ eidx,
                              const float* __restrict__ Y, float* __restrict__ E2) {
    int t = blockIdx.x * blockDim.x + threadIdx.x;
    int nz = t >> 1;
    int c4 = (t & 1) << 2;
    if (nz < NNZ) {
        int v = nidx[nz], e = eidx[nz];
        float4 val = *(const float4*)&Y[v * 8 + c4];
        float* dst = &E2[e * 8 + c4];
        atomicAdd(dst + 0, val.x);
        atomicAdd(dst + 1, val.y);
        atomicAdd(dst + 2, val.z);
        atomicAdd(dst + 3, val.w);
    }
}

// ---------------- scatter edge->node, 8 ch into d_out ----------------
__global__ void k_scatter_ev2(const int* __restrict__ nidx, const int* __restrict__ eidx,
                              const float* __restrict__ E2, const float* __restrict__ B,
                              float* __restrict__ outacc) {
    int t = blockIdx.x * blockDim.x + threadIdx.x;
    int nz = t >> 1;
    int c4 = (t & 1) << 2;
    if (nz < NNZ) {
        int v = nidx[nz], e = eidx[nz];
        float b = B[e];
        float binv = (b > 0.f) ? 1.f / b : 0.f;
        float4 val = *(const float4*)&E2[e * 8 + c4];
        float* dst = &outacc[v * 8 + c4];
        atomicAdd(dst + 0, val.x * binv);
        atomicAdd(dst + 1, val.y * binv);
        atomicAdd(dst + 2, val.z * binv);
        atomicAdd(dst + 3, val.w * binv);
    }
}

// ---------------- finalize layer2: out = out*Dinv + b2 (in place) ----------------
__global__ void k_finalize2(float* __restrict__ out, const float* __restrict__ D,
                            const float* __restrict__ b2) {
    int t = blockIdx.x * blockDim.x + threadIdx.x;
    int v = t >> 1;
    int c4 = (t & 1) << 2;
    if (v < N_NODES) {
        float d = D[v];
        float dinv = (d > 0.f) ? 1.f / d : 0.f;
        float4 a = *(float4*)&out[v * 8 + c4];
        float4 bb = *(const float4*)&b2[c4];
        float4 r;
        r.x = fmaf(a.x, dinv, bb.x);
        r.y = fmaf(a.y, dinv, bb.y);
        r.z = fmaf(a.z, dinv, bb.z);
        r.w = fmaf(a.w, dinv, bb.w);
        *(float4*)&out[v * 8 + c4] = r;
    }
}

extern "C" void kernel_launch(void* const* d_in, const int* in_sizes, int n_in,
                              void* d_out, int out_size, void* d_ws, size_t ws_size,
                              hipStream_t stream) {
    const float* x   = (const float*)d_in[0];
    const int*   ei  = (const int*)d_in[1];     // [2, NNZ]: row0 = node_idx, row1 = edge_idx
    const float* W1  = (const float*)d_in[2];
    const float* b1  = (const float*)d_in[3];
    const float* W2  = (const float*)d_in[4];
    const float* b2  = (const float*)d_in[5];
    const int* nidx = ei;
    const int* eidx = ei + NNZ;

    float* ws = (float*)d_ws;
    // workspace layout (floats)
    float* D    = ws;                          // 100000
    float* B    = D + N_NODES;                 // 50000
    float* xw   = B + N_HEDGES;                // 12.8M  (reused as node accumulator)
    float* S    = xw + (size_t)N_NODES * 128;  // 6.4M
    float* h    = S + (size_t)N_HEDGES * 128;  // 12.8M
    float* y2   = h + (size_t)N_NODES * 128;   // 0.8M
    float* E2   = y2 + (size_t)N_NODES * 8;    // 0.4M
    float* outp = (float*)d_out;

    // zero-init accumulators
    hipMemsetAsync(D, 0, (size_t)(N_NODES + N_HEDGES) * 4, stream);
    hipMemsetAsync(S, 0, (size_t)N_HEDGES * 128 * 4, stream);
    hipMemsetAsync(E2, 0, (size_t)N_HEDGES * 8 * 4, stream);
    hipMemsetAsync(d_out, 0, (size_t)N_NODES * 8 * 4, stream);

    k_degrees<<<(NNZ + 255) / 256, 256, 0, stream>>>(nidx, eidx, D, B);
    k_gemm1<<<(N_NODES + 63) / 64, 256, 0, stream>>>(x, W1, xw);
    k_scatter_ve<<<(NNZ * 32) / 256, 256, 0, stream>>>(nidx, eidx, xw, S);
    // reuse xw as node accumulator
    hipMemsetAsync(xw, 0, (size_t)N_NODES * 128 * 4, stream);
    k_scatter_ev<<<(NNZ * 32) / 256, 256, 0, stream>>>(nidx, eidx, S, B, xw);
    k_finalize1<<<(N_NODES * 32 + 255) / 256, 256, 0, stream>>>(xw, D, b1, h);
    k_gemm2<<<(N_NODES + 31) / 32, 256, 0, stream>>>(h, W2, y2);
    k_scatter_ve2<<<(NNZ * 2) / 256, 256, 0, stream>>>(nidx, eidx, y2, E2);
    k_scatter_ev2<<<(NNZ * 2) / 256, 256, 0, stream>>>(nidx, eidx, E2, B, outp);
    k_finalize2<<<(N_NODES * 2 + 255) / 256, 256, 0, stream>>>(outp, D, b2);
}

// Round 2
// 875.445 us; speedup vs baseline: 7.1985x; 7.1985x over previous
//
#include <hip/hip_runtime.h>
#include <hip/hip_bf16.h>

#define N_NODES  100000
#define N_HEDGES 50000
#define NNZ      1600000
#define IN_C     128
#define HID_C    128
#define N_CLS    8

// ---------------- degree counts (int) ----------------
__global__ void k_degrees(const int* __restrict__ nidx, const int* __restrict__ eidx,
                          int* __restrict__ deg_n, int* __restrict__ deg_e) {
    int i = blockIdx.x * blockDim.x + threadIdx.x;
    if (i < NNZ) {
        atomicAdd(&deg_n[nidx[i]], 1);
        atomicAdd(&deg_e[eidx[i]], 1);
    }
}

// ---------------- single-block exclusive scan: off[0]=0, off[i+1]=sum(cnt[0..i]) ----------------
__global__ __launch_bounds__(1024) void k_scan(const int* __restrict__ cnt, int n,
                                               int* __restrict__ off) {
    __shared__ int buf[1024];
    __shared__ int carry_s;
    const int tid = threadIdx.x;
    if (tid == 0) { carry_s = 0; off[0] = 0; }
    __syncthreads();
    for (int base = 0; base < n; base += 4096) {
        int carry = carry_s;
        int i0 = base + tid * 4;
        int v0 = (i0 + 0 < n) ? cnt[i0 + 0] : 0;
        int v1 = (i0 + 1 < n) ? cnt[i0 + 1] : 0;
        int v2 = (i0 + 2 < n) ? cnt[i0 + 2] : 0;
        int v3 = (i0 + 3 < n) ? cnt[i0 + 3] : 0;
        int s = v0 + v1 + v2 + v3;
        __syncthreads();
        buf[tid] = s;
        __syncthreads();
        for (int st = 1; st < 1024; st <<= 1) {
            int t = (tid >= st) ? buf[tid - st] : 0;
            __syncthreads();
            buf[tid] += t;
            __syncthreads();
        }
        int incl = buf[tid];
        int run = carry + incl - s;  // exclusive prefix for this thread's 4 elems
        if (i0 + 0 < n) { run += v0; off[i0 + 1] = run; }
        if (i0 + 1 < n) { run += v1; off[i0 + 2] = run; }
        if (i0 + 2 < n) { run += v2; off[i0 + 3] = run; }
        if (i0 + 3 < n) { run += v3; off[i0 + 4] = run; }
        __syncthreads();
        if (tid == 1023) carry_s = carry + incl;
        __syncthreads();
    }
}

// ---------------- fill adjacency lists ----------------
__global__ void k_fill(const int* __restrict__ nidx, const int* __restrict__ eidx,
                       const int* __restrict__ off_n, const int* __restrict__ off_e,
                       int* __restrict__ cur_n, int* __restrict__ cur_e,
                       int* __restrict__ list_n, int* __restrict__ list_e) {
    int i = blockIdx.x * blockDim.x + threadIdx.x;
    if (i < NNZ) {
        int v = nidx[i], e = eidx[i];
        int p = atomicAdd(&cur_e[e], 1);
        list_e[off_e[e] + p] = v;     // for edge e: incident node v
        int q = atomicAdd(&cur_n[v], 1);
        list_n[off_n[v] + q] = e;     // for node v: incident edge e
    }
}

// ---------------- GEMM1: XW = X @ W1  (100000x128 @ 128x128), fp32 ----------------
__global__ __launch_bounds__(256) void k_gemm1(const float* __restrict__ X,
                                               const float* __restrict__ W,
                                               float* __restrict__ XW) {
    __shared__ float sA[64 * 32];
    __shared__ float sB[32 * 128];
    const int tid = threadIdx.x;
    const int row0 = blockIdx.x * 64;
    const int tx = tid & 15, ty = tid >> 4;

    float acc[4][8];
#pragma unroll
    for (int r = 0; r < 4; r++)
#pragma unroll
        for (int c = 0; c < 8; c++) acc[r][c] = 0.f;

    for (int kt = 0; kt < 128; kt += 32) {
        {
            int idx = tid * 8;
            int ar = idx >> 5, ak = idx & 31;
            int grow = row0 + ar; if (grow >= N_NODES) grow = N_NODES - 1;
            const float4* src = (const float4*)&X[grow * 128 + kt + ak];
            float4 v0 = src[0], v1 = src[1];
            *(float4*)&sA[ar * 32 + ak] = v0;
            *(float4*)&sA[ar * 32 + ak + 4] = v1;
        }
        {
            int idx = tid * 16;
            int br = idx >> 7, bc = idx & 127;
            const float4* src = (const float4*)&W[(kt + br) * 128 + bc];
            float4 v0 = src[0], v1 = src[1], v2 = src[2], v3 = src[3];
            *(float4*)&sB[br * 128 + bc]      = v0;
            *(float4*)&sB[br * 128 + bc + 4]  = v1;
            *(float4*)&sB[br * 128 + bc + 8]  = v2;
            *(float4*)&sB[br * 128 + bc + 12] = v3;
        }
        __syncthreads();
#pragma unroll
        for (int kk = 0; kk < 32; kk++) {
            float a[4], b[8];
#pragma unroll
            for (int r = 0; r < 4; r++) a[r] = sA[(ty * 4 + r) * 32 + kk];
#pragma unroll
            for (int j = 0; j < 8; j++) b[j] = sB[kk * 128 + tx * 8 + j];
#pragma unroll
            for (int r = 0; r < 4; r++)
#pragma unroll
                for (int j = 0; j < 8; j++) acc[r][j] = fmaf(a[r], b[j], acc[r][j]);
        }
        __syncthreads();
    }
#pragma unroll
    for (int r = 0; r < 4; r++) {
        int grow = row0 + ty * 4 + r;
        if (grow < N_NODES) {
            float4 v0 = make_float4(acc[r][0], acc[r][1], acc[r][2], acc[r][3]);
            float4 v1 = make_float4(acc[r][4], acc[r][5], acc[r][6], acc[r][7]);
            *(float4*)&XW[grow * 128 + tx * 8]     = v0;
            *(float4*)&XW[grow * 128 + tx * 8 + 4] = v1;
        }
    }
}

// ---------------- edge gather L1: S[e] = Binv[e] * sum_{v in e} xw[v]  (wave/edge) ----------------
__global__ __launch_bounds__(256) void k_egather1(const int* __restrict__ off_e,
                                                  const int* __restrict__ list_e,
                                                  const float* __restrict__ xw,
                                                  float* __restrict__ S) {
    int w = (blockIdx.x * 256 + threadIdx.x) >> 6;
    int lane = threadIdx.x & 63;
    if (w >= N_HEDGES) return;
    int s0 = off_e[w], s1 = off_e[w + 1];
    float ax = 0.f, ay = 0.f;
    for (int base = s0; base < s1; base += 64) {
        int idx = (base + lane < s1) ? list_e[base + lane] : 0;
        int cnt = s1 - base; if (cnt > 64) cnt = 64;
        for (int j = 0; j < cnt; j++) {
            int u = __shfl(idx, j);
            float2 t = *(const float2*)&xw[(size_t)u * 128 + lane * 2];
            ax += t.x; ay += t.y;
        }
    }
    float binv = (s1 > s0) ? 1.f / (float)(s1 - s0) : 0.f;
    float2 r; r.x = ax * binv; r.y = ay * binv;
    *(float2*)&S[(size_t)w * 128 + lane * 2] = r;
}

// ---------------- node gather L1: h[v] = relu(Dinv[v] * sum_{e ∋ v} S[e] + b1) ----------------
__global__ __launch_bounds__(256) void k_ngather1(const int* __restrict__ off_n,
                                                  const int* __restrict__ list_n,
                                                  const float* __restrict__ S,
                                                  const float* __restrict__ b1,
                                                  float* __restrict__ h) {
    int w = (blockIdx.x * 256 + threadIdx.x) >> 6;
    int lane = threadIdx.x & 63;
    if (w >= N_NODES) return;
    int s0 = off_n[w], s1 = off_n[w + 1];
    float ax = 0.f, ay = 0.f;
    for (int base = s0; base < s1; base += 64) {
        int idx = (base + lane < s1) ? list_n[base + lane] : 0;
        int cnt = s1 - base; if (cnt > 64) cnt = 64;
        for (int j = 0; j < cnt; j++) {
            int e = __shfl(idx, j);
            float2 t = *(const float2*)&S[(size_t)e * 128 + lane * 2];
            ax += t.x; ay += t.y;
        }
    }
    float dinv = (s1 > s0) ? 1.f / (float)(s1 - s0) : 0.f;
    float2 bb = *(const float2*)&b1[lane * 2];
    float2 r;
    r.x = fmaxf(fmaf(ax, dinv, bb.x), 0.f);
    r.y = fmaxf(fmaf(ay, dinv, bb.y), 0.f);
    *(float2*)&h[(size_t)w * 128 + lane * 2] = r;
}

// ---------------- GEMM2: Y = H @ W2  (100000x128 @ 128x8) ----------------
__global__ __launch_bounds__(256) void k_gemm2(const float* __restrict__ H,
                                               const float* __restrict__ W2,
                                               float* __restrict__ Y) {
    __shared__ float sH[32 * 128];
    __shared__ float sW[128 * 8];
    const int tid = threadIdx.x;
    const int row0 = blockIdx.x * 32;
    {
        int i = tid * 4;
        *(float4*)&sW[i] = *(const float4*)&W2[i];
    }
    {
        int i = tid * 16;
        int r = i >> 7, c = i & 127;
        int g = row0 + r; if (g >= N_NODES) g = N_NODES - 1;
        const float4* src = (const float4*)&H[g * 128 + c];
        *(float4*)&sH[r * 128 + c]      = src[0];
        *(float4*)&sH[r * 128 + c + 4]  = src[1];
        *(float4*)&sH[r * 128 + c + 8]  = src[2];
        *(float4*)&sH[r * 128 + c + 12] = src[3];
    }
    __syncthreads();
    int r = tid >> 3, col = tid & 7;
    float acc = 0.f;
#pragma unroll
    for (int k = 0; k < 128; k++) acc = fmaf(sH[r * 128 + k], sW[k * 8 + col], acc);
    int g = row0 + r;
    if (g < N_NODES) Y[g * 8 + col] = acc;
}

// ---------------- edge gather L2 (8 ch): S2[e] = Binv[e] * sum y2[v] ----------------
__global__ void k_egather2(const int* __restrict__ off_e, const int* __restrict__ list_e,
                           const float* __restrict__ y2, float* __restrict__ S2) {
    int t = blockIdx.x * blockDim.x + threadIdx.x;
    if (t >= N_HEDGES * 8) return;
    int e = t >> 3, c = t & 7;
    int s0 = off_e[e], s1 = off_e[e + 1];
    float acc = 0.f;
    for (int j = s0; j < s1; j++) {
        int u = list_e[j];
        acc += y2[u * 8 + c];
    }
    float binv = (s1 > s0) ? 1.f / (float)(s1 - s0) : 0.f;
    S2[e * 8 + c] = acc * binv;
}

// ---------------- node gather L2 (8 ch): out[v] = Dinv[v] * sum S2[e] + b2 ----------------
__global__ void k_ngather2(const int* __restrict__ off_n, const int* __restrict__ list_n,
                           const float* __restrict__ S2, const float* __restrict__ b2,
                           float* __restrict__ out) {
    int t = blockIdx.x * blockDim.x + threadIdx.x;
    if (t >= N_NODES * 8) return;
    int v = t >> 3, c = t & 7;
    int s0 = off_n[v], s1 = off_n[v + 1];
    float acc = 0.f;
    for (int j = s0; j < s1; j++) {
        int e = list_n[j];
        acc += S2[e * 8 + c];
    }
    float dinv = (s1 > s0) ? 1.f / (float)(s1 - s0) : 0.f;
    out[v * 8 + c] = fmaf(acc, dinv, b2[c]);
}

extern "C" void kernel_launch(void* const* d_in, const int* in_sizes, int n_in,
                              void* d_out, int out_size, void* d_ws, size_t ws_size,
                              hipStream_t stream) {
    const float* x   = (const float*)d_in[0];
    const int*   ei  = (const int*)d_in[1];     // [2, NNZ]: row0 = node_idx, row1 = edge_idx
    const float* W1  = (const float*)d_in[2];
    const float* b1  = (const float*)d_in[3];
    const float* W2  = (const float*)d_in[4];
    const float* b2  = (const float*)d_in[5];
    const int* nidx = ei;
    const int* eidx = ei + NNZ;

    // ---- workspace layout ----
    int* ip     = (int*)d_ws;
    int* deg_n  = ip;                        // 100000
    int* deg_e  = deg_n + N_NODES;           // 50000
    int* cur_n  = deg_e + N_HEDGES;          // 100000
    int* cur_e  = cur_n + N_NODES;           // 50000
    int* off_n  = cur_e + N_HEDGES;          // 100001
    int* off_e  = off_n + N_NODES + 1;       // 50001
    int* list_e = off_e + N_HEDGES + 1;      // NNZ (nodes per edge)
    int* list_n = list_e + NNZ;              // NNZ (edges per node)
    float* fb   = (float*)(list_n + NNZ + 2);  // 16B-aligned
    float* xw   = fb;                          // 12.8M  (reused as h)
    float* S    = xw + (size_t)N_NODES * 128;  // 6.4M
    float* y2   = S + (size_t)N_HEDGES * 128;  // 0.8M
    float* S2   = y2 + (size_t)N_NODES * 8;    // 0.4M
    float* outp = (float*)d_out;

    // zero only the counters (everything else is fully overwritten)
    hipMemsetAsync(ip, 0, (size_t)(2 * N_NODES + 2 * N_HEDGES) * 4, stream);

    k_degrees<<<(NNZ + 255) / 256, 256, 0, stream>>>(nidx, eidx, deg_n, deg_e);
    k_scan<<<1, 1024, 0, stream>>>(deg_e, N_HEDGES, off_e);
    k_scan<<<1, 1024, 0, stream>>>(deg_n, N_NODES, off_n);
    k_fill<<<(NNZ + 255) / 256, 256, 0, stream>>>(nidx, eidx, off_n, off_e,
                                                  cur_n, cur_e, list_n, list_e);
    k_gemm1<<<(N_NODES + 63) / 64, 256, 0, stream>>>(x, W1, xw);
    k_egather1<<<(N_HEDGES * 64 + 255) / 256, 256, 0, stream>>>(off_e, list_e, xw, S);
    k_ngather1<<<(N_NODES * 64 + 255) / 256, 256, 0, stream>>>(off_n, list_n, S, b1, xw);
    k_gemm2<<<(N_NODES + 31) / 32, 256, 0, stream>>>(xw, W2, y2);
    k_egather2<<<(N_HEDGES * 8 + 255) / 256, 256, 0, stream>>>(off_e, list_e, y2, S2);
    k_ngather2<<<(N_NODES * 8 + 255) / 256, 256, 0, stream>>>(off_n, list_n, S2, b2, outp);
}

// Round 3
// 627.202 us; speedup vs baseline: 10.0476x; 1.3958x over previous
//
#include <hip/hip_runtime.h>
#include <hip/hip_bf16.h>

#define N_NODES  100000
#define N_HEDGES 50000
#define NNZ      1600000
#define IN_C     128
#define HID_C    128
#define N_CLS    8

#define BE 13   // ceil(N_HEDGES/4096)
#define BN 25   // ceil(N_NODES/4096)

// ---------------- degree counts + per-nnz rank (int) ----------------
__global__ void k_degrees(const int* __restrict__ nidx, const int* __restrict__ eidx,
                          int* __restrict__ deg_n, int* __restrict__ deg_e,
                          int* __restrict__ rank_n, int* __restrict__ rank_e) {
    int i = blockIdx.x * blockDim.x + threadIdx.x;
    if (i < NNZ) {
        rank_n[i] = atomicAdd(&deg_n[nidx[i]], 1);
        rank_e[i] = atomicAdd(&deg_e[eidx[i]], 1);
    }
}

// ---------------- hierarchical scan, stage 1: per-4096-chunk scan ----------------
__global__ __launch_bounds__(1024) void k_scan1(const int* __restrict__ deg_e, int* __restrict__ off_e,
                                                const int* __restrict__ deg_n, int* __restrict__ off_n,
                                                int* __restrict__ part) {
    int gb = blockIdx.x;
    const int* cnt; int* off; int n; int b; int* ps;
    if (gb < BE) { cnt = deg_e; off = off_e; n = N_HEDGES; b = gb; ps = part; }
    else         { cnt = deg_n; off = off_n; n = N_NODES;  b = gb - BE; ps = part + 32; }
    const int tid = threadIdx.x, lane = tid & 63, wid = tid >> 6;
    int i0 = b * 4096 + tid * 4;
    int v0 = (i0 + 0 < n) ? cnt[i0 + 0] : 0;
    int v1 = (i0 + 1 < n) ? cnt[i0 + 1] : 0;
    int v2 = (i0 + 2 < n) ? cnt[i0 + 2] : 0;
    int v3 = (i0 + 3 < n) ? cnt[i0 + 3] : 0;
    int s = v0 + v1 + v2 + v3;
    int incl = s;
#pragma unroll
    for (int d = 1; d < 64; d <<= 1) {
        int t = __shfl_up(incl, d);
        if (lane >= d) incl += t;
    }
    __shared__ int wsum[16];
    __shared__ int wbase[16];
    if (lane == 63) wsum[wid] = incl;
    __syncthreads();
    if (tid == 0) {
        int r = 0;
#pragma unroll
        for (int k = 0; k < 16; k++) { wbase[k] = r; r += wsum[k]; }
        ps[b] = r;
    }
    __syncthreads();
    int run = wbase[wid] + incl - s;  // exclusive prefix (chunk-local)
    if (i0 + 0 < n) { run += v0; off[i0 + 1] = run; }
    if (i0 + 1 < n) { run += v1; off[i0 + 2] = run; }
    if (i0 + 2 < n) { run += v2; off[i0 + 3] = run; }
    if (i0 + 3 < n) { run += v3; off[i0 + 4] = run; }
}

// ---------------- stage 2: scan the chunk totals (tiny) ----------------
__global__ void k_scan2(int* __restrict__ part) {
    int t = threadIdx.x;
    if (t == 0) { int r = 0; for (int k = 0; k < BE; k++) { int x = part[k]; part[k] = r; r += x; } }
    if (t == 1) { int r = 0; for (int k = 0; k < BN; k++) { int x = part[32 + k]; part[32 + k] = r; r += x; } }
}

// ---------------- stage 3: add chunk bases ----------------
__global__ __launch_bounds__(1024) void k_scan3(int* __restrict__ off_e, int* __restrict__ off_n,
                                                const int* __restrict__ part) {
    int gb = blockIdx.x;
    int* off; int n; int b; int add;
    if (gb < BE) { off = off_e; n = N_HEDGES; b = gb; add = part[b]; }
    else         { off = off_n; n = N_NODES;  b = gb - BE; add = part[32 + b]; }
    int tid = threadIdx.x;
    int i0 = b * 4096 + tid * 4;
    if (b == 0 && tid == 0) off[0] = 0;
#pragma unroll
    for (int k = 0; k < 4; k++)
        if (i0 + k < n) off[i0 + 1 + k] += add;
}

// ---------------- fill adjacency lists (atomic-free) ----------------
__global__ void k_fill(const int* __restrict__ nidx, const int* __restrict__ eidx,
                       const int* __restrict__ rank_n, const int* __restrict__ rank_e,
                       const int* __restrict__ off_n, const int* __restrict__ off_e,
                       int* __restrict__ list_n, int* __restrict__ list_e) {
    int i = blockIdx.x * blockDim.x + threadIdx.x;
    if (i < NNZ) {
        int v = nidx[i], e = eidx[i];
        list_e[off_e[e] + rank_e[i]] = v;
        list_n[off_n[v] + rank_n[i]] = e;
    }
}

// ---------------- GEMM1: XW = X @ W1  (100000x128 @ 128x128), fp32 ----------------
__global__ __launch_bounds__(256) void k_gemm1(const float* __restrict__ X,
                                               const float* __restrict__ W,
                                               float* __restrict__ XW) {
    __shared__ float sA[64 * 32];
    __shared__ float sB[32 * 128];
    const int tid = threadIdx.x;
    const int row0 = blockIdx.x * 64;
    const int tx = tid & 15, ty = tid >> 4;

    float acc[4][8];
#pragma unroll
    for (int r = 0; r < 4; r++)
#pragma unroll
        for (int c = 0; c < 8; c++) acc[r][c] = 0.f;

    for (int kt = 0; kt < 128; kt += 32) {
        {
            int idx = tid * 8;
            int ar = idx >> 5, ak = idx & 31;
            int grow = row0 + ar; if (grow >= N_NODES) grow = N_NODES - 1;
            const float4* src = (const float4*)&X[grow * 128 + kt + ak];
            float4 v0 = src[0], v1 = src[1];
            *(float4*)&sA[ar * 32 + ak] = v0;
            *(float4*)&sA[ar * 32 + ak + 4] = v1;
        }
        {
            int idx = tid * 16;
            int br = idx >> 7, bc = idx & 127;
            const float4* src = (const float4*)&W[(kt + br) * 128 + bc];
            float4 v0 = src[0], v1 = src[1], v2 = src[2], v3 = src[3];
            *(float4*)&sB[br * 128 + bc]      = v0;
            *(float4*)&sB[br * 128 + bc + 4]  = v1;
            *(float4*)&sB[br * 128 + bc + 8]  = v2;
            *(float4*)&sB[br * 128 + bc + 12] = v3;
        }
        __syncthreads();
#pragma unroll
        for (int kk = 0; kk < 32; kk++) {
            float a[4], b[8];
#pragma unroll
            for (int r = 0; r < 4; r++) a[r] = sA[(ty * 4 + r) * 32 + kk];
#pragma unroll
            for (int j = 0; j < 8; j++) b[j] = sB[kk * 128 + tx * 8 + j];
#pragma unroll
            for (int r = 0; r < 4; r++)
#pragma unroll
                for (int j = 0; j < 8; j++) acc[r][j] = fmaf(a[r], b[j], acc[r][j]);
        }
        __syncthreads();
    }
#pragma unroll
    for (int r = 0; r < 4; r++) {
        int grow = row0 + ty * 4 + r;
        if (grow < N_NODES) {
            float4 v0 = make_float4(acc[r][0], acc[r][1], acc[r][2], acc[r][3]);
            float4 v1 = make_float4(acc[r][4], acc[r][5], acc[r][6], acc[r][7]);
            *(float4*)&XW[grow * 128 + tx * 8]     = v0;
            *(float4*)&XW[grow * 128 + tx * 8 + 4] = v1;
        }
    }
}

// ---------------- edge gather L1: S[e] = Binv[e] * sum_{v in e} xw[v]  (wave/edge) ----------------
__global__ __launch_bounds__(256) void k_egather1(const int* __restrict__ off_e,
                                                  const int* __restrict__ list_e,
                                                  const float* __restrict__ xw,
                                                  float* __restrict__ S) {
    int w = (blockIdx.x * 256 + threadIdx.x) >> 6;
    int lane = threadIdx.x & 63;
    if (w >= N_HEDGES) return;
    int s0 = off_e[w], s1 = off_e[w + 1];
    float ax = 0.f, ay = 0.f;
    for (int base = s0; base < s1; base += 64) {
        int rem = s1 - base;
        int cnt = rem > 64 ? 64 : rem;
        int idx = (lane < cnt) ? list_e[base + lane] : 0;
        int j = 0;
        for (; j + 4 <= cnt; j += 4) {
            int u0 = __shfl(idx, j + 0), u1 = __shfl(idx, j + 1);
            int u2 = __shfl(idx, j + 2), u3 = __shfl(idx, j + 3);
            float2 t0 = *(const float2*)&xw[(size_t)u0 * 128 + lane * 2];
            float2 t1 = *(const float2*)&xw[(size_t)u1 * 128 + lane * 2];
            float2 t2 = *(const float2*)&xw[(size_t)u2 * 128 + lane * 2];
            float2 t3 = *(const float2*)&xw[(size_t)u3 * 128 + lane * 2];
            ax += t0.x + t1.x; ay += t0.y + t1.y;
            ax += t2.x + t3.x; ay += t2.y + t3.y;
        }
        for (; j < cnt; j++) {
            int u = __shfl(idx, j);
            float2 t = *(const float2*)&xw[(size_t)u * 128 + lane * 2];
            ax += t.x; ay += t.y;
        }
    }
    float binv = (s1 > s0) ? 1.f / (float)(s1 - s0) : 0.f;
    float2 r; r.x = ax * binv; r.y = ay * binv;
    *(float2*)&S[(size_t)w * 128 + lane * 2] = r;
}

// ---------------- node gather L1 fused with GEMM2:
// h[v] = relu(Dinv[v]*sum S[e] + b1) held in registers, y2[v] = h[v] @ W2 ----------------
__global__ __launch_bounds__(256) void k_ngather1g(const int* __restrict__ off_n,
                                                   const int* __restrict__ list_n,
                                                   const float* __restrict__ S,
                                                   const float* __restrict__ b1,
                                                   const float* __restrict__ W2,
                                                   float* __restrict__ y2) {
    int w = (blockIdx.x * 256 + threadIdx.x) >> 6;
    int lane = threadIdx.x & 63;
    if (w >= N_NODES) return;
    // per-lane W2 rows (2*lane, 2*lane+1): 16 consecutive floats
    float wreg[16];
    {
        const float4* wp = (const float4*)&W2[16 * lane];
#pragma unroll
        for (int q = 0; q < 4; q++) {
            float4 t = wp[q];
            wreg[4 * q + 0] = t.x; wreg[4 * q + 1] = t.y;
            wreg[4 * q + 2] = t.z; wreg[4 * q + 3] = t.w;
        }
    }
    int s0 = off_n[w], s1 = off_n[w + 1];
    float ax = 0.f, ay = 0.f;
    for (int base = s0; base < s1; base += 64) {
        int rem = s1 - base;
        int cnt = rem > 64 ? 64 : rem;
        int idx = (lane < cnt) ? list_n[base + lane] : 0;
        int j = 0;
        for (; j + 4 <= cnt; j += 4) {
            int e0 = __shfl(idx, j + 0), e1 = __shfl(idx, j + 1);
            int e2 = __shfl(idx, j + 2), e3 = __shfl(idx, j + 3);
            float2 t0 = *(const float2*)&S[(size_t)e0 * 128 + lane * 2];
            float2 t1 = *(const float2*)&S[(size_t)e1 * 128 + lane * 2];
            float2 t2 = *(const float2*)&S[(size_t)e2 * 128 + lane * 2];
            float2 t3 = *(const float2*)&S[(size_t)e3 * 128 + lane * 2];
            ax += t0.x + t1.x; ay += t0.y + t1.y;
            ax += t2.x + t3.x; ay += t2.y + t3.y;
        }
        for (; j < cnt; j++) {
            int e = __shfl(idx, j);
            float2 t = *(const float2*)&S[(size_t)e * 128 + lane * 2];
            ax += t.x; ay += t.y;
        }
    }
    float dinv = (s1 > s0) ? 1.f / (float)(s1 - s0) : 0.f;
    float2 bb = *(const float2*)&b1[lane * 2];
    float h0 = fmaxf(fmaf(ax, dinv, bb.x), 0.f);
    float h1 = fmaxf(fmaf(ay, dinv, bb.y), 0.f);
    // y2[v][c] = sum_k h[k] * W2[k][c]
    float p[8];
#pragma unroll
    for (int c = 0; c < 8; c++) p[c] = h0 * wreg[c] + h1 * wreg[8 + c];
#pragma unroll
    for (int c = 0; c < 8; c++) {
        float vsum = p[c];
#pragma unroll
        for (int off = 32; off; off >>= 1) vsum += __shfl_xor(vsum, off);
        p[c] = vsum;
    }
    float outv = p[0];
#pragma unroll
    for (int c = 1; c < 8; c++) outv = (lane == c) ? p[c] : outv;
    if (lane < 8) y2[(size_t)w * 8 + lane] = outv;
}

// ---------------- edge gather L2 (8 ch): S2[e] = Binv[e] * sum y2[v] ----------------
__global__ void k_egather2(const int* __restrict__ off_e, const int* __restrict__ list_e,
                           const float* __restrict__ y2, float* __restrict__ S2) {
    int t = blockIdx.x * blockDim.x + threadIdx.x;
    if (t >= N_HEDGES * 8) return;
    int e = t >> 3, c = t & 7;
    int s0 = off_e[e], s1 = off_e[e + 1];
    float acc = 0.f;
    for (int j = s0; j < s1; j++) {
        int u = list_e[j];
        acc += y2[u * 8 + c];
    }
    float binv = (s1 > s0) ? 1.f / (float)(s1 - s0) : 0.f;
    S2[e * 8 + c] = acc * binv;
}

// ---------------- node gather L2 (8 ch): out[v] = Dinv[v] * sum S2[e] + b2 ----------------
__global__ void k_ngather2(const int* __restrict__ off_n, const int* __restrict__ list_n,
                           const float* __restrict__ S2, const float* __restrict__ b2,
                           float* __restrict__ out) {
    int t = blockIdx.x * blockDim.x + threadIdx.x;
    if (t >= N_NODES * 8) return;
    int v = t >> 3, c = t & 7;
    int s0 = off_n[v], s1 = off_n[v + 1];
    float acc = 0.f;
    for (int j = s0; j < s1; j++) {
        int e = list_n[j];
        acc += S2[e * 8 + c];
    }
    float dinv = (s1 > s0) ? 1.f / (float)(s1 - s0) : 0.f;
    out[v * 8 + c] = fmaf(acc, dinv, b2[c]);
}

extern "C" void kernel_launch(void* const* d_in, const int* in_sizes, int n_in,
                              void* d_out, int out_size, void* d_ws, size_t ws_size,
                              hipStream_t stream) {
    const float* x   = (const float*)d_in[0];
    const int*   ei  = (const int*)d_in[1];     // [2, NNZ]: row0 = node_idx, row1 = edge_idx
    const float* W1  = (const float*)d_in[2];
    const float* b1  = (const float*)d_in[3];
    const float* W2  = (const float*)d_in[4];
    const float* b2  = (const float*)d_in[5];
    const int* nidx = ei;
    const int* eidx = ei + NNZ;

    // ---- workspace layout ----
    int* ip     = (int*)d_ws;
    int* deg_n  = ip;                        // 100000
    int* deg_e  = deg_n + N_NODES;           // 50000
    int* off_n  = deg_e + N_HEDGES;          // 100001
    int* off_e  = off_n + N_NODES + 1;       // 50001
    int* part   = off_e + N_HEDGES + 1;      // 64
    int* list_e = part + 64;                 // NNZ (nodes per edge)
    int* list_n = list_e + NNZ;              // NNZ (edges per node)
    size_t int_count = (size_t)(list_n + NNZ - ip);
    int_count = (int_count + 3) & ~(size_t)3;            // 16B align
    float* fb   = (float*)(ip + int_count);
    float* xw   = fb;                          // 12.8M floats (rank arrays alias its head)
    float* S    = xw + (size_t)N_NODES * 128;  // 6.4M
    float* y2   = S + (size_t)N_HEDGES * 128;  // 0.8M
    float* S2   = y2 + (size_t)N_NODES * 8;    // 0.4M
    float* outp = (float*)d_out;
    // rank arrays: alias xw region (dead once k_fill completes, before k_gemm1 writes xw)
    int* rank_e = (int*)xw;
    int* rank_n = rank_e + NNZ;

    // zero only the degree counters
    hipMemsetAsync(deg_n, 0, (size_t)(N_NODES + N_HEDGES) * 4, stream);

    k_degrees<<<(NNZ + 255) / 256, 256, 0, stream>>>(nidx, eidx, deg_n, deg_e, rank_n, rank_e);
    k_scan1<<<BE + BN, 1024, 0, stream>>>(deg_e, off_e, deg_n, off_n, part);
    k_scan2<<<1, 64, 0, stream>>>(part);
    k_scan3<<<BE + BN, 1024, 0, stream>>>(off_e, off_n, part);
    k_fill<<<(NNZ + 255) / 256, 256, 0, stream>>>(nidx, eidx, rank_n, rank_e,
                                                  off_n, off_e, list_n, list_e);
    k_gemm1<<<(N_NODES + 63) / 64, 256, 0, stream>>>(x, W1, xw);
    k_egather1<<<(N_HEDGES * 64 + 255) / 256, 256, 0, stream>>>(off_e, list_e, xw, S);
    k_ngather1g<<<(N_NODES * 64 + 255) / 256, 256, 0, stream>>>(off_n, list_n, S, b1, W2, y2);
    k_egather2<<<(N_HEDGES * 8 + 255) / 256, 256, 0, stream>>>(off_e, list_e, y2, S2);
    k_ngather2<<<(N_NODES * 8 + 255) / 256, 256, 0, stream>>>(off_n, list_n, S2, b2, outp);
}

// Round 4
// 533.759 us; speedup vs baseline: 11.8066x; 1.1751x over previous
//
#include <hip/hip_runtime.h>
#include <hip/hip_bf16.h>
#include <hip/hip_fp16.h>

#define N_NODES  100000
#define N_HEDGES 50000
#define NNZ      1600000
#define IN_C     128
#define HID_C    128
#define N_CLS    8

#define BE 13   // ceil(N_HEDGES/4096)
#define BN 25   // ceil(N_NODES/4096)

#define NB_DEG ((NNZ + 255) / 256)      // 6250
#define NB_G1  ((N_NODES + 63) / 64)    // 1563

// ---------------- merged: degree counts + rank  ||  GEMM1 (fp16 out) ----------------
__global__ __launch_bounds__(256) void k_deg_gemm1(
        const int* __restrict__ nidx, const int* __restrict__ eidx,
        int* __restrict__ deg_n, int* __restrict__ deg_e,
        int* __restrict__ rank_n, int* __restrict__ rank_e,
        const float* __restrict__ X, const float* __restrict__ W,
        __half* __restrict__ XWH) {
    __shared__ float sA[64 * 32];
    __shared__ float sB[32 * 128];
    if (blockIdx.x < NB_DEG) {
        int i = blockIdx.x * 256 + threadIdx.x;
        if (i < NNZ) {
            rank_n[i] = atomicAdd(&deg_n[nidx[i]], 1);
            rank_e[i] = atomicAdd(&deg_e[eidx[i]], 1);
        }
        return;
    }
    const int bid = blockIdx.x - NB_DEG;
    const int tid = threadIdx.x;
    const int row0 = bid * 64;
    const int tx = tid & 15, ty = tid >> 4;

    float acc[4][8];
#pragma unroll
    for (int r = 0; r < 4; r++)
#pragma unroll
        for (int c = 0; c < 8; c++) acc[r][c] = 0.f;

    for (int kt = 0; kt < 128; kt += 32) {
        {
            int idx = tid * 8;
            int ar = idx >> 5, ak = idx & 31;
            int grow = row0 + ar; if (grow >= N_NODES) grow = N_NODES - 1;
            const float4* src = (const float4*)&X[(size_t)grow * 128 + kt + ak];
            float4 v0 = src[0], v1 = src[1];
            *(float4*)&sA[ar * 32 + ak] = v0;
            *(float4*)&sA[ar * 32 + ak + 4] = v1;
        }
        {
            int idx = tid * 16;
            int br = idx >> 7, bc = idx & 127;
            const float4* src = (const float4*)&W[(size_t)(kt + br) * 128 + bc];
            float4 v0 = src[0], v1 = src[1], v2 = src[2], v3 = src[3];
            *(float4*)&sB[br * 128 + bc]      = v0;
            *(float4*)&sB[br * 128 + bc + 4]  = v1;
            *(float4*)&sB[br * 128 + bc + 8]  = v2;
            *(float4*)&sB[br * 128 + bc + 12] = v3;
        }
        __syncthreads();
#pragma unroll
        for (int kk = 0; kk < 32; kk++) {
            float a[4], b[8];
#pragma unroll
            for (int r = 0; r < 4; r++) a[r] = sA[(ty * 4 + r) * 32 + kk];
#pragma unroll
            for (int j = 0; j < 8; j++) b[j] = sB[kk * 128 + tx * 8 + j];
#pragma unroll
            for (int r = 0; r < 4; r++)
#pragma unroll
                for (int j = 0; j < 8; j++) acc[r][j] = fmaf(a[r], b[j], acc[r][j]);
        }
        __syncthreads();
    }
#pragma unroll
    for (int r = 0; r < 4; r++) {
        int grow = row0 + ty * 4 + r;
        if (grow < N_NODES) {
            __half2 p0 = __floats2half2_rn(acc[r][0], acc[r][1]);
            __half2 p1 = __floats2half2_rn(acc[r][2], acc[r][3]);
            __half2 p2 = __floats2half2_rn(acc[r][4], acc[r][5]);
            __half2 p3 = __floats2half2_rn(acc[r][6], acc[r][7]);
            __half2* dst = (__half2*)&XWH[(size_t)grow * 128 + tx * 8];
            dst[0] = p0; dst[1] = p1; dst[2] = p2; dst[3] = p3;
        }
    }
}

// ---------------- hierarchical scan, stage 1: per-4096-chunk scan ----------------
__global__ __launch_bounds__(1024) void k_scan1(const int* __restrict__ deg_e, int* __restrict__ off_e,
                                                const int* __restrict__ deg_n, int* __restrict__ off_n,
                                                int* __restrict__ part) {
    int gb = blockIdx.x;
    const int* cnt; int* off; int n; int b; int* ps;
    if (gb < BE) { cnt = deg_e; off = off_e; n = N_HEDGES; b = gb; ps = part; }
    else         { cnt = deg_n; off = off_n; n = N_NODES;  b = gb - BE; ps = part + 32; }
    const int tid = threadIdx.x, lane = tid & 63, wid = tid >> 6;
    int i0 = b * 4096 + tid * 4;
    int v0 = (i0 + 0 < n) ? cnt[i0 + 0] : 0;
    int v1 = (i0 + 1 < n) ? cnt[i0 + 1] : 0;
    int v2 = (i0 + 2 < n) ? cnt[i0 + 2] : 0;
    int v3 = (i0 + 3 < n) ? cnt[i0 + 3] : 0;
    int s = v0 + v1 + v2 + v3;
    int incl = s;
#pragma unroll
    for (int d = 1; d < 64; d <<= 1) {
        int t = __shfl_up(incl, d);
        if (lane >= d) incl += t;
    }
    __shared__ int wsum[16];
    __shared__ int wbase[16];
    if (lane == 63) wsum[wid] = incl;
    __syncthreads();
    if (tid == 0) {
        int r = 0;
#pragma unroll
        for (int k = 0; k < 16; k++) { wbase[k] = r; r += wsum[k]; }
        ps[b] = r;
    }
    __syncthreads();
    int run = wbase[wid] + incl - s;
    if (i0 + 0 < n) { run += v0; off[i0 + 1] = run; }
    if (i0 + 1 < n) { run += v1; off[i0 + 2] = run; }
    if (i0 + 2 < n) { run += v2; off[i0 + 3] = run; }
    if (i0 + 3 < n) { run += v3; off[i0 + 4] = run; }
}

// ---------------- stage 2: scan the chunk totals (tiny) ----------------
__global__ void k_scan2(int* __restrict__ part) {
    int t = threadIdx.x;
    if (t == 0) { int r = 0; for (int k = 0; k < BE; k++) { int x = part[k]; part[k] = r; r += x; } }
    if (t == 1) { int r = 0; for (int k = 0; k < BN; k++) { int x = part[32 + k]; part[32 + k] = r; r += x; } }
}

// ---------------- stage 3: add chunk bases ----------------
__global__ __launch_bounds__(1024) void k_scan3(int* __restrict__ off_e, int* __restrict__ off_n,
                                                const int* __restrict__ part) {
    int gb = blockIdx.x;
    int* off; int n; int b; int add;
    if (gb < BE) { off = off_e; n = N_HEDGES; b = gb; add = part[b]; }
    else         { off = off_n; n = N_NODES;  b = gb - BE; add = part[32 + b]; }
    int tid = threadIdx.x;
    int i0 = b * 4096 + tid * 4;
    if (b == 0 && tid == 0) off[0] = 0;
#pragma unroll
    for (int k = 0; k < 4; k++)
        if (i0 + k < n) off[i0 + 1 + k] += add;
}

// ---------------- fill adjacency lists (atomic-free) ----------------
__global__ void k_fill(const int* __restrict__ nidx, const int* __restrict__ eidx,
                       const int* __restrict__ rank_n, const int* __restrict__ rank_e,
                       const int* __restrict__ off_n, const int* __restrict__ off_e,
                       int* __restrict__ list_n, int* __restrict__ list_e) {
    int i = blockIdx.x * blockDim.x + threadIdx.x;
    if (i < NNZ) {
        int v = nidx[i], e = eidx[i];
        list_e[off_e[e] + rank_e[i]] = v;
        list_n[off_n[v] + rank_n[i]] = e;
    }
}

// ---------------- edge gather L1 (fp16 payload): S[e] = Binv[e] * sum xw[v] ----------------
__global__ __launch_bounds__(256) void k_egather1(const int* __restrict__ off_e,
                                                  const int* __restrict__ list_e,
                                                  const __half2* __restrict__ xw2,
                                                  __half2* __restrict__ S2h) {
    int w = (blockIdx.x * 256 + threadIdx.x) >> 6;
    int lane = threadIdx.x & 63;
    if (w >= N_HEDGES) return;
    int s0 = off_e[w], s1 = off_e[w + 1];
    float ax = 0.f, ay = 0.f;
    for (int base = s0; base < s1; base += 64) {
        int rem = s1 - base;
        int cnt = rem > 64 ? 64 : rem;
        int idx = (lane < cnt) ? list_e[base + lane] : 0;
        int j = 0;
        for (; j + 4 <= cnt; j += 4) {
            int u0 = __shfl(idx, j + 0), u1 = __shfl(idx, j + 1);
            int u2 = __shfl(idx, j + 2), u3 = __shfl(idx, j + 3);
            float2 t0 = __half22float2(xw2[(size_t)u0 * 64 + lane]);
            float2 t1 = __half22float2(xw2[(size_t)u1 * 64 + lane]);
            float2 t2 = __half22float2(xw2[(size_t)u2 * 64 + lane]);
            float2 t3 = __half22float2(xw2[(size_t)u3 * 64 + lane]);
            ax += t0.x + t1.x; ay += t0.y + t1.y;
            ax += t2.x + t3.x; ay += t2.y + t3.y;
        }
        for (; j < cnt; j++) {
            int u = __shfl(idx, j);
            float2 t = __half22float2(xw2[(size_t)u * 64 + lane]);
            ax += t.x; ay += t.y;
        }
    }
    float binv = (s1 > s0) ? 1.f / (float)(s1 - s0) : 0.f;
    S2h[(size_t)w * 64 + lane] = __floats2half2_rn(ax * binv, ay * binv);
}

// ---------------- node gather L1 (fp16 payload) fused with GEMM2 ----------------
__global__ __launch_bounds__(256) void k_ngather1g(const int* __restrict__ off_n,
                                                   const int* __restrict__ list_n,
                                                   const __half2* __restrict__ S2h,
                                                   const float* __restrict__ b1,
                                                   const float* __restrict__ W2,
                                                   float* __restrict__ y2) {
    int w = (blockIdx.x * 256 + threadIdx.x) >> 6;
    int lane = threadIdx.x & 63;
    if (w >= N_NODES) return;
    float wreg[16];
    {
        const float4* wp = (const float4*)&W2[16 * lane];
#pragma unroll
        for (int q = 0; q < 4; q++) {
            float4 t = wp[q];
            wreg[4 * q + 0] = t.x; wreg[4 * q + 1] = t.y;
            wreg[4 * q + 2] = t.z; wreg[4 * q + 3] = t.w;
        }
    }
    int s0 = off_n[w], s1 = off_n[w + 1];
    float ax = 0.f, ay = 0.f;
    for (int base = s0; base < s1; base += 64) {
        int rem = s1 - base;
        int cnt = rem > 64 ? 64 : rem;
        int idx = (lane < cnt) ? list_n[base + lane] : 0;
        int j = 0;
        for (; j + 4 <= cnt; j += 4) {
            int e0 = __shfl(idx, j + 0), e1 = __shfl(idx, j + 1);
            int e2 = __shfl(idx, j + 2), e3 = __shfl(idx, j + 3);
            float2 t0 = __half22float2(S2h[(size_t)e0 * 64 + lane]);
            float2 t1 = __half22float2(S2h[(size_t)e1 * 64 + lane]);
            float2 t2 = __half22float2(S2h[(size_t)e2 * 64 + lane]);
            float2 t3 = __half22float2(S2h[(size_t)e3 * 64 + lane]);
            ax += t0.x + t1.x; ay += t0.y + t1.y;
            ax += t2.x + t3.x; ay += t2.y + t3.y;
        }
        for (; j < cnt; j++) {
            int e = __shfl(idx, j);
            float2 t = __half22float2(S2h[(size_t)e * 64 + lane]);
            ax += t.x; ay += t.y;
        }
    }
    float dinv = (s1 > s0) ? 1.f / (float)(s1 - s0) : 0.f;
    float2 bb = *(const float2*)&b1[lane * 2];
    float h0 = fmaxf(fmaf(ax, dinv, bb.x), 0.f);
    float h1 = fmaxf(fmaf(ay, dinv, bb.y), 0.f);
    float p[8];
#pragma unroll
    for (int c = 0; c < 8; c++) p[c] = h0 * wreg[c] + h1 * wreg[8 + c];
#pragma unroll
    for (int c = 0; c < 8; c++) {
        float vsum = p[c];
#pragma unroll
        for (int off = 32; off; off >>= 1) vsum += __shfl_xor(vsum, off);
        p[c] = vsum;
    }
    float outv = p[0];
#pragma unroll
    for (int c = 1; c < 8; c++) outv = (lane == c) ? p[c] : outv;
    if (lane < 8) y2[(size_t)w * 8 + lane] = outv;
}

// ---------------- edge gather L2 (8 ch, fp32): S2[e] = Binv[e] * sum y2[v] ----------------
__global__ void k_egather2(const int* __restrict__ off_e, const int* __restrict__ list_e,
                           const float* __restrict__ y2, float* __restrict__ S2) {
    int t = blockIdx.x * blockDim.x + threadIdx.x;
    if (t >= N_HEDGES * 8) return;
    int e = t >> 3, c = t & 7;
    int s0 = off_e[e], s1 = off_e[e + 1];
    float acc = 0.f;
    for (int j = s0; j < s1; j++) {
        int u = list_e[j];
        acc += y2[u * 8 + c];
    }
    float binv = (s1 > s0) ? 1.f / (float)(s1 - s0) : 0.f;
    S2[e * 8 + c] = acc * binv;
}

// ---------------- node gather L2 (8 ch): out[v] = Dinv[v] * sum S2[e] + b2 ----------------
__global__ void k_ngather2(const int* __restrict__ off_n, const int* __restrict__ list_n,
                           const float* __restrict__ S2, const float* __restrict__ b2,
                           float* __restrict__ out) {
    int t = blockIdx.x * blockDim.x + threadIdx.x;
    if (t >= N_NODES * 8) return;
    int v = t >> 3, c = t & 7;
    int s0 = off_n[v], s1 = off_n[v + 1];
    float acc = 0.f;
    for (int j = s0; j < s1; j++) {
        int e = list_n[j];
        acc += S2[e * 8 + c];
    }
    float dinv = (s1 > s0) ? 1.f / (float)(s1 - s0) : 0.f;
    out[v * 8 + c] = fmaf(acc, dinv, b2[c]);
}

extern "C" void kernel_launch(void* const* d_in, const int* in_sizes, int n_in,
                              void* d_out, int out_size, void* d_ws, size_t ws_size,
                              hipStream_t stream) {
    const float* x   = (const float*)d_in[0];
    const int*   ei  = (const int*)d_in[1];     // [2, NNZ]: row0 = node_idx, row1 = edge_idx
    const float* W1  = (const float*)d_in[2];
    const float* b1  = (const float*)d_in[3];
    const float* W2  = (const float*)d_in[4];
    const float* b2  = (const float*)d_in[5];
    const int* nidx = ei;
    const int* eidx = ei + NNZ;

    // ---- workspace layout ----
    int* ip     = (int*)d_ws;
    int* deg_n  = ip;                        // 100000
    int* deg_e  = deg_n + N_NODES;           // 50000
    int* off_n  = deg_e + N_HEDGES;          // 100001
    int* off_e  = off_n + N_NODES + 1;       // 50001
    int* part   = off_e + N_HEDGES + 1;      // 64
    int* list_e = part + 64;                 // NNZ (nodes per edge)
    int* list_n = list_e + NNZ;              // NNZ (edges per node)
    int* rank_n = list_n + NNZ;              // NNZ (no aliasing: gemm1 runs concurrently)
    int* rank_e = rank_n + NNZ;              // NNZ
    size_t int_count = (size_t)(rank_e + NNZ - ip);
    int_count = (int_count + 3) & ~(size_t)3;            // 16B align
    __half* xwh = (__half*)(ip + int_count);             // N_NODES*128 fp16 (25.6 MB)
    __half* Sh  = xwh + (size_t)N_NODES * 128;           // N_HEDGES*128 fp16 (12.8 MB)
    float* fb   = (float*)(Sh + (size_t)N_HEDGES * 128);
    float* y2   = fb;                          // N_NODES*8
    float* S2   = y2 + (size_t)N_NODES * 8;    // N_HEDGES*8
    float* outp = (float*)d_out;

    // zero only the degree counters
    hipMemsetAsync(deg_n, 0, (size_t)(N_NODES + N_HEDGES) * 4, stream);

    k_deg_gemm1<<<NB_DEG + NB_G1, 256, 0, stream>>>(nidx, eidx, deg_n, deg_e,
                                                    rank_n, rank_e, x, W1, xwh);
    k_scan1<<<BE + BN, 1024, 0, stream>>>(deg_e, off_e, deg_n, off_n, part);
    k_scan2<<<1, 64, 0, stream>>>(part);
    k_scan3<<<BE + BN, 1024, 0, stream>>>(off_e, off_n, part);
    k_fill<<<(NNZ + 255) / 256, 256, 0, stream>>>(nidx, eidx, rank_n, rank_e,
                                                  off_n, off_e, list_n, list_e);
    k_egather1<<<(N_HEDGES * 64 + 255) / 256, 256, 0, stream>>>(off_e, list_e,
                                                                (const __half2*)xwh, (__half2*)Sh);
    k_ngather1g<<<(N_NODES * 64 + 255) / 256, 256, 0, stream>>>(off_n, list_n,
                                                                (const __half2*)Sh, b1, W2, y2);
    k_egather2<<<(N_HEDGES * 8 + 255) / 256, 256, 0, stream>>>(off_e, list_e, y2, S2);
    k_ngather2<<<(N_NODES * 8 + 255) / 256, 256, 0, stream>>>(off_n, list_n, S2, b2, outp);
}